// Round 23
// baseline (116.253 us; speedup 1.0000x reference)
//
#include <hip/hip_runtime.h>

typedef _Float16 f16x8 __attribute__((ext_vector_type(8)));
typedef _Float16 f16x4 __attribute__((ext_vector_type(4)));
typedef float f32x4 __attribute__((ext_vector_type(4)));

#define MFMA32(a, b, c) __builtin_amdgcn_mfma_f32_16x16x32_f16(a, b, c, 0, 0, 0)
#define MFMA16(a, b, c) __builtin_amdgcn_mfma_f32_16x16x16f16(a, b, c, 0, 0, 0)

// ---------------------------------------------------------------- converts
__global__ __launch_bounds__(256) void convert_all(
    const float* __restrict__ x,
    const float* __restrict__ w0, const float* __restrict__ w1,
    const float* __restrict__ w2, const float* __restrict__ w3,
    _Float16* __restrict__ xb,
    _Float16* __restrict__ o0, _Float16* __restrict__ o1,
    _Float16* __restrict__ o2, _Float16* __restrict__ o3) {
  int chunk = blockIdx.x * 256 + threadIdx.x;
  const float* in;
  _Float16* out;
  int i;
  if (chunk < 1048576) {
    in = x; out = xb; i = chunk * 4;
  } else {
    int t = chunk - 1048576;
    int z = t >> 18;
    i = (t & 262143) * 4;
    in = (z == 0) ? w0 : (z == 1) ? w1 : (z == 2) ? w2 : w3;
    out = (z == 0) ? o0 : (z == 1) ? o1 : (z == 2) ? o2 : o3;
  }
  float4 v = *(const float4*)(in + i);
  f16x4 h;
  h.x = (_Float16)v.x; h.y = (_Float16)v.y; h.z = (_Float16)v.z; h.w = (_Float16)v.w;
  *(f16x4*)(out + i) = h;
}

// ---------------------------------------------------------------- staging
// T2 swizzle via PRE-SWIZZLED GLOBAL SOURCE (r22-proven): lane loads global
// chunk (lane&7)^(row&7) -> LDS chunk c of row R holds global chunk c^(R&7).
// Fragment reads XOR the same key -> 16-way bank conflict becomes 2-way.
__device__ __forceinline__ void gld_lds16(_Float16* l, const _Float16* g) {
  __builtin_amdgcn_global_load_lds(
      (const __attribute__((address_space(1))) unsigned int*)g,
      (__attribute__((address_space(3))) unsigned int*)l, 16, 0, 0);
}

// stage a 128x64 f16 tile into linear LDS (16 blocks of 8 rows x 64 halves)
__device__ __forceinline__ void stage128(_Float16* lds, const _Float16* g,
                                         int wid, int lane) {
  int rl = (lane >> 3) & 7;
  int col = ((lane & 7) ^ rl) * 8;           // pre-swizzled source column
#pragma unroll
  for (int j = 0; j < 4; ++j) {
    int blk = wid * 4 + j;
    int row = blk * 8 + rl;
    gld_lds16(lds + blk * 512, g + (size_t)row * 1024 + col);
  }
}

// 128x128 GEMM core (r8-proven structure + swizzle): BK=64, 4 waves 2x2,
// each wave 64x64 (acc 4x4). 16 MFMA per 8 ds_read_b128 per K-step (2.0
// MFMA/read vs 1.33 at 64x128) — lowers LDS cycles/FLOP by 33%.
__device__ __forceinline__ void gemm_core128(const _Float16* __restrict__ A,
                                             const _Float16* __restrict__ W,
                                             _Float16* As, _Float16* Bs,
                                             f32x4 acc[4][4], int m0, int n0, int tid) {
  int lane = tid & 63, wid = tid >> 6;
  int lr = lane & 15, lg = lane >> 4;
  int wm = (wid >> 1) * 64, wn = (wid & 1) * 64;
  int key = lr & 7;
  for (int k0 = 0; k0 < 1024; k0 += 64) {
    __syncthreads();
    stage128(As, A + (size_t)m0 * 1024 + k0, wid, lane);
    stage128(Bs, W + (size_t)n0 * 1024 + k0, wid, lane);
    __syncthreads();
#pragma unroll
    for (int ks = 0; ks < 2; ++ks) {
      int coff = ((ks * 4 + lg) ^ key) << 3; // swizzled chunk offset (halves)
      f16x8 af[4], bfv[4];
#pragma unroll
      for (int mf = 0; mf < 4; ++mf)
        af[mf] = *(const f16x8*)(As + (wm + mf * 16 + lr) * 64 + coff);
#pragma unroll
      for (int nf = 0; nf < 4; ++nf)
        bfv[nf] = *(const f16x8*)(Bs + (wn + nf * 16 + lr) * 64 + coff);
#pragma unroll
      for (int mf = 0; mf < 4; ++mf)
#pragma unroll
        for (int nf = 0; nf < 4; ++nf)
          acc[mf][nf] = MFMA32(af[mf], bfv[nf], acc[mf][nf]);
    }
  }
}

// --------------------------------------------------- QKV projection GEMM
// grid (32, 8, 3): XCD = bx%8 -> A-panel L2-local across n and z.
#define TRP 136  // V-transpose buffer stride (halves), r8-proven

__global__ __launch_bounds__(256) void proj_gemm(
    const _Float16* __restrict__ xb,
    const _Float16* __restrict__ wq, const _Float16* __restrict__ wk,
    const _Float16* __restrict__ wv,
    const float* __restrict__ bq, const float* __restrict__ bk,
    const float* __restrict__ bv,
    _Float16* __restrict__ qo, _Float16* __restrict__ ko, _Float16* __restrict__ vo) {
  __shared__ __align__(16) _Float16 smem[16384];   // As 8192 + Bs 8192 (32KB)
  _Float16* As = smem;
  _Float16* Bs = smem + 8192;
  int z = blockIdx.z;
  const _Float16* W = (z == 0) ? wq : ((z == 1) ? wk : wv);
  const float* bias = (z == 0) ? bq : ((z == 1) ? bk : bv);
  int tid = threadIdx.x;
  int m0 = blockIdx.x * 128, n0 = blockIdx.y * 128;
  f32x4 acc[4][4] = {};
  gemm_core128(xb, W, As, Bs, acc, m0, n0, tid);

  int lane = tid & 63, wid = tid >> 6;
  int lr = lane & 15, lg = lane >> 4;
  int wm = (wid >> 1) * 64, wn = (wid & 1) * 64;

  if (z == 2) {
    // r8-proven two-phase transpose epilogue: Tr[64][TRP], coalesced stores
    _Float16* Tr = smem;                 // 64*136 = 8704 <= 16384
    int b = m0 >> 11, s0 = m0 & 2047;
    __syncthreads();
#pragma unroll
    for (int half = 0; half < 2; ++half) {
      if ((wid & 1) == half) {           // waves owning cols [half*64, +64)
#pragma unroll
        for (int nf = 0; nf < 4; ++nf) {
          int c = nf * 16 + lr;          // local col 0..63
          float bb = bias[n0 + half * 64 + c];
#pragma unroll
          for (int mf = 0; mf < 4; ++mf)
#pragma unroll
            for (int i = 0; i < 4; ++i)
              Tr[c * TRP + wm + mf * 16 + lg * 4 + i] = (_Float16)(acc[mf][nf][i] + bb);
        }
      }
      __syncthreads();
      int h = (n0 >> 6) + half;
#pragma unroll
      for (int j = 0; j < 4; ++j) {      // 1024 chunks of 8 halves
        int cid = tid + 256 * j;
        int c = cid >> 4, seg = cid & 15;
        f16x8 v = *(const f16x8*)(Tr + c * TRP + seg * 8);
        *(f16x8*)(vo + ((size_t)(b * 16 + h) * 64 + c) * 2048 + s0 + seg * 8) = v;
      }
      __syncthreads();
    }
  } else {
    _Float16* o = (z == 0) ? qo : ko;
#pragma unroll
    for (int nf = 0; nf < 4; ++nf) {
      int col = n0 + wn + nf * 16 + lr;
      float bb = bias[col];
      int h = col >> 6, hd = col & 63;
#pragma unroll
      for (int mf = 0; mf < 4; ++mf)
#pragma unroll
        for (int i = 0; i < 4; ++i) {
          int row = m0 + wm + mf * 16 + lg * 4 + i;
          int b = row >> 11, s = row & 2047;
          o[((size_t)(b * 16 + h) * 2048 + s) * 64 + hd] = (_Float16)(acc[mf][nf][i] + bb);
        }
    }
  }
}

// --------------------------------------------------------- output GEMM (f32)
__global__ __launch_bounds__(256) void out_gemm(
    const _Float16* __restrict__ attn, const _Float16* __restrict__ wo,
    const float* __restrict__ bo, float* __restrict__ out) {
  __shared__ __align__(16) _Float16 smem[16384];
  _Float16* As = smem;
  _Float16* Bs = smem + 8192;
  int tid = threadIdx.x;
  int m0 = blockIdx.x * 128, n0 = blockIdx.y * 128;
  f32x4 acc[4][4] = {};
  gemm_core128(attn, wo, As, Bs, acc, m0, n0, tid);

  int lane = tid & 63, wid = tid >> 6;
  int lr = lane & 15, lg = lane >> 4;
  int wm = (wid >> 1) * 64, wn = (wid & 1) * 64;
#pragma unroll
  for (int nf = 0; nf < 4; ++nf) {
    int col = n0 + wn + nf * 16 + lr;
    float bb = bo[col];
#pragma unroll
    for (int mf = 0; mf < 4; ++mf)
#pragma unroll
      for (int i = 0; i < 4; ++i) {
        int row = m0 + wm + mf * 16 + lg * 4 + i;
        out[(size_t)row * 1024 + col] = acc[mf][nf][i] + bb;
      }
  }
}

// --------------------------------------------------------- flash attention v17
// (byte-identical to r21/r22 — PASSED at 46us: kv-parity split, 512 thr,
// launch_bounds(512,2), in-LDS combine, complementary qt, head-x grid.)
#define LDP 72  // padded LDS stride (halves)

template <bool MASK>
__device__ __forceinline__ void attn_tile32(const _Float16* Ks, const _Float16* Vs,
                                            const f16x8 qb[2][2], int kv0, int qwb,
                                            int lr, int lg,
                                            float m[2], float l[2], f32x4 ot[2][4]) {
  const float L2E = 1.44269504f;
  const float NINF = -__builtin_inff();
  f16x8 kf0[4], kf1[4];
#pragma unroll
  for (int nf = 0; nf < 4; ++nf) {
    kf0[nf] = *(const f16x8*)(Ks + (nf * 16 + lr) * LDP + lg * 8);
    kf1[nf] = *(const f16x8*)(Ks + (nf * 16 + lr) * LDP + 32 + lg * 8);
  }
  f32x4 sc[2][4];
#pragma unroll
  for (int h = 0; h < 2; ++h)
#pragma unroll
    for (int nf = 0; nf < 4; ++nf) {
      f32x4 z = {0.f, 0.f, 0.f, 0.f};
      z = MFMA32(kf0[nf], qb[h][0], z);
      z = MFMA32(kf1[nf], qb[h][1], z);
      sc[h][nf] = z;
    }
  if (MASK) {
#pragma unroll
    for (int h = 0; h < 2; ++h) {
      int qg = qwb + h * 16 + lr;
#pragma unroll
      for (int nf = 0; nf < 4; ++nf)
#pragma unroll
        for (int i = 0; i < 4; ++i) {
          int kg = kv0 + nf * 16 + lg * 4 + i;
          sc[h][nf][i] = (kg <= qg) ? sc[h][nf][i] : NINF;
        }
    }
  }
  f16x4 pf[2][4];
#pragma unroll
  for (int h = 0; h < 2; ++h) {
    f32x4 mx4 = sc[h][0];
#pragma unroll
    for (int nf = 1; nf < 4; ++nf)
#pragma unroll
      for (int i = 0; i < 4; ++i) mx4[i] = fmaxf(mx4[i], sc[h][nf][i]);
    float tm = fmaxf(fmaxf(mx4[0], mx4[1]), fmaxf(mx4[2], mx4[3]));
    tm = fmaxf(tm, __shfl_xor(tm, 16));
    tm = fmaxf(tm, __shfl_xor(tm, 32));
    float mn = fmaxf(m[h], tm);
    float alpha = __builtin_amdgcn_exp2f((m[h] - mn) * L2E);
    m[h] = mn;
    float mnL = mn * L2E;
    float ps = 0.f;
#pragma unroll
    for (int nf = 0; nf < 4; ++nf)
#pragma unroll
      for (int i = 0; i < 4; ++i) {
        float p = __builtin_amdgcn_exp2f(sc[h][nf][i] * L2E - mnL);
        ps += p;
        pf[h][nf][i] = (_Float16)p;
      }
    ps += __shfl_xor(ps, 16);
    ps += __shfl_xor(ps, 32);
    l[h] = l[h] * alpha + ps;
#pragma unroll
    for (int dt = 0; dt < 4; ++dt)
#pragma unroll
      for (int i = 0; i < 4; ++i) ot[h][dt][i] *= alpha;
  }
#pragma unroll
  for (int nf = 0; nf < 4; ++nf)
#pragma unroll
    for (int dt = 0; dt < 4; ++dt) {
      f16x4 vf = *(const f16x4*)(Vs + (dt * 16 + lr) * LDP + nf * 16 + lg * 4);
      ot[0][dt] = MFMA16(vf, pf[0][nf], ot[0][dt]);
      ot[1][dt] = MFMA16(vf, pf[1][nf], ot[1][dt]);
    }
}

__global__ __launch_bounds__(512, 2) void attn_kernel(
    const _Float16* __restrict__ Q, const _Float16* __restrict__ K,
    const _Float16* __restrict__ VT, _Float16* __restrict__ O) {
  __shared__ __align__(16) _Float16 smem[18432];
  _Float16* KsA = smem;
  _Float16* KsB = smem + 4608;
  _Float16* VsA = smem + 9216;
  _Float16* VsB = smem + 13824;
  const float L2E = 1.44269504f;

  int tid = threadIdx.x, lane = tid & 63, wid = tid >> 6;
  int grp = wid >> 2;                  // 0: even tiles, 1: odd tiles
  int wq4 = wid & 3;                   // q sub-block within group
  int hh = blockIdx.x;                 // head on x -> XCD = hh%8 (K/V L2-local)
  int qt = blockIdx.z ? (15 - (int)blockIdx.y) : (int)blockIdx.y;
  int b = blockIdx.z;
  size_t hoff = (size_t)(b * 16 + hh) * 2048 * 64;
  const _Float16* Qh = Q + hoff;
  const _Float16* Kh = K + hoff;
  const _Float16* VTh = VT + hoff;
  int qwb = qt * 128 + wq4 * 32;
  int lr = lane & 15, lg = lane >> 4;

  f16x8 qb[2][2];
#pragma unroll
  for (int h = 0; h < 2; ++h) {
    const _Float16* qp = Qh + (size_t)(qwb + h * 16 + lr) * 64;
    qb[h][0] = *(const f16x8*)(qp + lg * 8);
    qb[h][1] = *(const f16x8*)(qp + 32 + lg * 8);
#pragma unroll
    for (int j = 0; j < 8; ++j) {      // fold 1/sqrt(64) into Q (exact: 2^-3)
      qb[h][0][j] *= (_Float16)0.125f;
      qb[h][1][j] *= (_Float16)0.125f;
    }
  }

  float m[2] = {-__builtin_inff(), -__builtin_inff()};
  float l[2] = {0.f, 0.f};
  f32x4 ot[2][4] = {};

  int rr = tid >> 3, cc = (tid & 7) * 8;    // rr in 0..63
  int4 rka = *(const int4*)(Kh + (size_t)rr * 64 + cc);
  int4 rkb = *(const int4*)(Kh + (size_t)(64 + rr) * 64 + cc);
  int4 rva = *(const int4*)(VTh + (size_t)rr * 2048 + cc);
  int4 rvb = *(const int4*)(VTh + (size_t)rr * 2048 + 64 + cc);
  *(int4*)(KsA + rr * LDP + cc) = rka;
  *(int4*)(KsB + rr * LDP + cc) = rkb;
  *(int4*)(VsA + rr * LDP + cc) = rva;
  *(int4*)(VsB + rr * LDP + cc) = rvb;
  __syncthreads();

  int aw = qwb >> 6;                   // this wave's masked tile (global index)
  for (int p = 0; p <= qt; ++p) {
    if (p < qt) {                      // issue pair p+1 loads before compute
      int ka = (p + 1) * 128, kb = ka + 64;
      rka = *(const int4*)(Kh + (size_t)(ka + rr) * 64 + cc);
      rkb = *(const int4*)(Kh + (size_t)(kb + rr) * 64 + cc);
      rva = *(const int4*)(VTh + (size_t)rr * 2048 + ka + cc);
      rvb = *(const int4*)(VTh + (size_t)rr * 2048 + kb + cc);
    }
    int tm = 2 * p + grp;              // this group's tile this pair
    const _Float16* Ks = grp ? KsB : KsA;
    const _Float16* Vs = grp ? VsB : VsA;
    if (tm < aw)
      attn_tile32<false>(Ks, Vs, qb, tm * 64, qwb, lr, lg, m, l, ot);
    else if (tm == aw)
      attn_tile32<true>(Ks, Vs, qb, tm * 64, qwb, lr, lg, m, l, ot);
    __syncthreads();                   // all reads of pair p complete
    if (p < qt) {
      *(int4*)(KsA + rr * LDP + cc) = rka;
      *(int4*)(KsB + rr * LDP + cc) = rkb;
      *(int4*)(VsA + rr * LDP + cc) = rva;
      *(int4*)(VsB + rr * LDP + cc) = rvb;
      __syncthreads();                 // pair p+1 visible
    }
  }

  // ---- intra-block combine: group B -> LDS, group A merges and writes O ----
  float* Cmb = (float*)smem;           // 36*256*4 = 36864 B (exact reuse)
  if (grp == 1) {
    int base = wq4 * 64 + lane;
#pragma unroll
    for (int h = 0; h < 2; ++h) {
      Cmb[(h * 18 + 0) * 256 + base] = m[h];
      Cmb[(h * 18 + 1) * 256 + base] = l[h];
#pragma unroll
      for (int dt = 0; dt < 4; ++dt)
#pragma unroll
        for (int i = 0; i < 4; ++i)
          Cmb[(h * 18 + 2 + dt * 4 + i) * 256 + base] = ot[h][dt][i];
    }
  }
  __syncthreads();
  if (grp == 0) {
    int base = wq4 * 64 + lane;
#pragma unroll
    for (int h = 0; h < 2; ++h) {
      float mB = Cmb[(h * 18 + 0) * 256 + base];
      float lB = Cmb[(h * 18 + 1) * 256 + base];
      float ms = fmaxf(m[h], mB);
      float fA = __builtin_amdgcn_exp2f((m[h] - ms) * L2E);
      float fB = __builtin_amdgcn_exp2f((mB - ms) * L2E);
      float inv = 1.f / (fA * l[h] + fB * lB);
      fA *= inv; fB *= inv;
      _Float16* Oh = O + ((size_t)b * 2048 + qwb + h * 16 + lr) * 1024 + hh * 64;
#pragma unroll
      for (int dt = 0; dt < 4; ++dt) {
        f16x4 o;
#pragma unroll
        for (int i = 0; i < 4; ++i)
          o[i] = (_Float16)(fA * ot[h][dt][i] +
                            fB * Cmb[(h * 18 + 2 + dt * 4 + i) * 256 + base]);
        *(f16x4*)(Oh + dt * 16 + lg * 4) = o;
      }
    }
  }
}

// ------------------------------------------------------------------- launch
extern "C" void kernel_launch(void* const* d_in, const int* in_sizes, int n_in,
                              void* d_out, int out_size, void* d_ws, size_t ws_size,
                              hipStream_t stream) {
  const float* x  = (const float*)d_in[0];
  const float* Wq = (const float*)d_in[1];
  const float* bq = (const float*)d_in[2];
  const float* Wk = (const float*)d_in[3];
  const float* bk = (const float*)d_in[4];
  const float* Wv = (const float*)d_in[5];
  const float* bv = (const float*)d_in[6];
  const float* Wo = (const float*)d_in[7];
  const float* bo = (const float*)d_in[8];
  float* out = (float*)d_out;

  _Float16* ws  = (_Float16*)d_ws;
  _Float16* xb  = ws;
  _Float16* wqb = ws + 4194304;
  _Float16* wkb = ws + 5242880;
  _Float16* wvb = ws + 6291456;
  _Float16* wob = ws + 7340032;
  _Float16* qw  = ws + 8388608;       // [B,H,S,64]
  _Float16* kw  = ws + 12582912;      // [B,H,S,64]
  _Float16* vtw = ws + 16777216;      // [B,H,64,S]
  _Float16* aw  = ws + 20971520;      // [B,S,1024]

  convert_all<<<8192, 256, 0, stream>>>(x, Wq, Wk, Wv, Wo,
                                        xb, wqb, wkb, wvb, wob);

  proj_gemm<<<dim3(32, 8, 3), 256, 0, stream>>>(xb, wqb, wkb, wvb, bq, bk, bv,
                                                qw, kw, vtw);
  attn_kernel<<<dim3(16, 16, 2), 512, 0, stream>>>(qw, kw, vtw, aw);
  out_gemm<<<dim3(32, 8), 256, 0, stream>>>(aw, wob, bo, out);
}

// Round 24
// 111.556 us; speedup vs baseline: 1.0421x; 1.0421x over previous
//
#include <hip/hip_runtime.h>

typedef _Float16 f16x8 __attribute__((ext_vector_type(8)));
typedef _Float16 f16x4 __attribute__((ext_vector_type(4)));
typedef float f32x4 __attribute__((ext_vector_type(4)));

#define MFMA32(a, b, c) __builtin_amdgcn_mfma_f32_16x16x32_f16(a, b, c, 0, 0, 0)
#define MFMA16(a, b, c) __builtin_amdgcn_mfma_f32_16x16x16f16(a, b, c, 0, 0, 0)

// ---------------------------------------------------------------- converts
__global__ __launch_bounds__(256) void convert_all(
    const float* __restrict__ x,
    const float* __restrict__ w0, const float* __restrict__ w1,
    const float* __restrict__ w2, const float* __restrict__ w3,
    _Float16* __restrict__ xb,
    _Float16* __restrict__ o0, _Float16* __restrict__ o1,
    _Float16* __restrict__ o2, _Float16* __restrict__ o3) {
  int chunk = blockIdx.x * 256 + threadIdx.x;
  const float* in;
  _Float16* out;
  int i;
  if (chunk < 1048576) {
    in = x; out = xb; i = chunk * 4;
  } else {
    int t = chunk - 1048576;
    int z = t >> 18;
    i = (t & 262143) * 4;
    in = (z == 0) ? w0 : (z == 1) ? w1 : (z == 2) ? w2 : w3;
    out = (z == 0) ? o0 : (z == 1) ? o1 : (z == 2) ? o2 : o3;
  }
  float4 v = *(const float4*)(in + i);
  f16x4 h;
  h.x = (_Float16)v.x; h.y = (_Float16)v.y; h.z = (_Float16)v.z; h.w = (_Float16)v.w;
  *(f16x4*)(out + i) = h;
}

// ---------------------------------------------------------------- staging
// T2 swizzle via PRE-SWIZZLED GLOBAL SOURCE (r22-proven): LDS chunk c of row
// R holds global chunk c^(R&7); fragment reads XOR the same key.
__device__ __forceinline__ void gld_lds16(_Float16* l, const _Float16* g) {
  __builtin_amdgcn_global_load_lds(
      (const __attribute__((address_space(1))) unsigned int*)g,
      (__attribute__((address_space(3))) unsigned int*)l, 16, 0, 0);
}

// ---- 256-thread (4-wave) staging, r22-proven (out_gemm) ----
__device__ __forceinline__ void stage64(_Float16* lds, const _Float16* g,
                                        int wid, int lane) {
  int rl = (lane >> 3) & 7;
  int col = ((lane & 7) ^ rl) * 8;
#pragma unroll
  for (int j = 0; j < 2; ++j) {
    int blk = wid * 2 + j;
    gld_lds16(lds + blk * 512, g + (size_t)(blk * 8 + rl) * 1024 + col);
  }
}

__device__ __forceinline__ void stage128(_Float16* lds, const _Float16* g,
                                         int wid, int lane) {
  int rl = (lane >> 3) & 7;
  int col = ((lane & 7) ^ rl) * 8;
#pragma unroll
  for (int j = 0; j < 4; ++j) {
    int blk = wid * 4 + j;
    gld_lds16(lds + blk * 512, g + (size_t)(blk * 8 + rl) * 1024 + col);
  }
}

// r22-proven 64x128 4-wave core (out_gemm keeps it)
__device__ __forceinline__ void gemm_core64(const _Float16* __restrict__ A,
                                            const _Float16* __restrict__ W,
                                            _Float16* As, _Float16* Bs,
                                            f32x4 acc[4][2], int m0, int n0, int tid) {
  int lane = tid & 63, wid = tid >> 6;
  int lr = lane & 15, lg = lane >> 4;
  int wn = wid * 32;
  int key = lr & 7;
  for (int k0 = 0; k0 < 1024; k0 += 64) {
    __syncthreads();
    stage64(As, A + (size_t)m0 * 1024 + k0, wid, lane);
    stage128(Bs, W + (size_t)n0 * 1024 + k0, wid, lane);
    __syncthreads();
#pragma unroll
    for (int ks = 0; ks < 2; ++ks) {
      int coff = ((ks * 4 + lg) ^ key) << 3;
      f16x8 af[4], bfv[2];
#pragma unroll
      for (int mf = 0; mf < 4; ++mf)
        af[mf] = *(const f16x8*)(As + (mf * 16 + lr) * 64 + coff);
#pragma unroll
      for (int nf = 0; nf < 2; ++nf)
        bfv[nf] = *(const f16x8*)(Bs + (wn + nf * 16 + lr) * 64 + coff);
#pragma unroll
      for (int mf = 0; mf < 4; ++mf)
#pragma unroll
        for (int nf = 0; nf < 2; ++nf)
          acc[mf][nf] = MFMA32(af[mf], bfv[nf], acc[mf][nf]);
    }
  }
}

// --------------------------------------------------- QKV projection GEMM
// v2 core: 2 waves (128 thr) per 64x128 tile; each wave 64x64 (acc 4x4).
// 16 MFMA per 8 ds_read_b128 per ks (2.0 MFMA/read vs 1.33) — 33% fewer LDS
// reads/FLOP — while KEEPING grid (64,8,3) = 1536 blocks = 6/CU.
#define TRP 72

__device__ __forceinline__ void stage64_t128(_Float16* lds, const _Float16* g,
                                             int tid) {
  int rl = (tid >> 3) & 7;
  int col = ((tid & 7) ^ rl) * 8;
  int half = tid >> 6;
#pragma unroll
  for (int j = 0; j < 4; ++j) {
    int blk = j * 2 + half;                  // 8-row block 0..7
    gld_lds16(lds + blk * 512, g + (size_t)(blk * 8 + rl) * 1024 + col);
  }
}

__device__ __forceinline__ void stage128_t128(_Float16* lds, const _Float16* g,
                                              int tid) {
  int rl = (tid >> 3) & 7;
  int col = ((tid & 7) ^ rl) * 8;
  int half = tid >> 6;
#pragma unroll
  for (int j = 0; j < 8; ++j) {
    int blk = j * 2 + half;                  // 8-row block 0..15
    gld_lds16(lds + blk * 512, g + (size_t)(blk * 8 + rl) * 1024 + col);
  }
}

__global__ __launch_bounds__(128) void proj_gemm(
    const _Float16* __restrict__ xb,
    const _Float16* __restrict__ wq, const _Float16* __restrict__ wk,
    const _Float16* __restrict__ wv,
    const float* __restrict__ bq, const float* __restrict__ bk,
    const float* __restrict__ bv,
    _Float16* __restrict__ qo, _Float16* __restrict__ ko, _Float16* __restrict__ vo) {
  __shared__ __align__(16) _Float16 smem[12288];   // As 4096 + Bs 8192 halves
  _Float16* As = smem;
  _Float16* Bs = smem + 4096;
  int z = blockIdx.z;
  const _Float16* W = (z == 0) ? wq : ((z == 1) ? wk : wv);
  const float* bias = (z == 0) ? bq : ((z == 1) ? bk : bv);
  int tid = threadIdx.x;
  int lane = tid & 63, wid = tid >> 6;       // wid 0..1
  int lr = lane & 15, lg = lane >> 4;
  int wn = wid * 64;
  int key = lr & 7;
  int m0 = blockIdx.x * 64, n0 = blockIdx.y * 128;

  f32x4 acc[4][4] = {};
  for (int k0 = 0; k0 < 1024; k0 += 64) {
    __syncthreads();
    stage64_t128(As, xb + (size_t)m0 * 1024 + k0, tid);
    stage128_t128(Bs, W + (size_t)n0 * 1024 + k0, tid);
    __syncthreads();
#pragma unroll
    for (int ks = 0; ks < 2; ++ks) {
      int coff = ((ks * 4 + lg) ^ key) << 3;
      f16x8 af[4], bfv[4];
#pragma unroll
      for (int mf = 0; mf < 4; ++mf)
        af[mf] = *(const f16x8*)(As + (mf * 16 + lr) * 64 + coff);
#pragma unroll
      for (int nf = 0; nf < 4; ++nf)
        bfv[nf] = *(const f16x8*)(Bs + (wn + nf * 16 + lr) * 64 + coff);
#pragma unroll
      for (int mf = 0; mf < 4; ++mf)
#pragma unroll
        for (int nf = 0; nf < 4; ++nf)
          acc[mf][nf] = MFMA32(af[mf], bfv[nf], acc[mf][nf]);
    }
  }

  if (z == 2) {
    _Float16* Tr = smem;                 // 128*72 = 9216 <= 12288
    int b = m0 >> 11, s0 = m0 & 2047;
    __syncthreads();
#pragma unroll
    for (int nf = 0; nf < 4; ++nf) {
      int c = wn + nf * 16 + lr;
      float bb = bias[n0 + c];
#pragma unroll
      for (int mf = 0; mf < 4; ++mf)
#pragma unroll
        for (int i = 0; i < 4; ++i)
          Tr[c * TRP + mf * 16 + lg * 4 + i] = (_Float16)(acc[mf][nf][i] + bb);
    }
    __syncthreads();
#pragma unroll
    for (int j = 0; j < 8; ++j) {        // 1024 chunks of 8 halves, 128 thr
      int cid = tid + 128 * j;
      int c = cid >> 3, seg = cid & 7;
      int cg = n0 + c, h = cg >> 6, hd = cg & 63;
      f16x8 v = *(const f16x8*)(Tr + c * TRP + seg * 8);
      *(f16x8*)(vo + ((size_t)(b * 16 + h) * 64 + hd) * 2048 + s0 + seg * 8) = v;
    }
  } else {
    _Float16* o = (z == 0) ? qo : ko;
#pragma unroll
    for (int nf = 0; nf < 4; ++nf) {
      int col = n0 + wn + nf * 16 + lr;
      float bb = bias[col];
      int h = col >> 6, hd = col & 63;
#pragma unroll
      for (int mf = 0; mf < 4; ++mf)
#pragma unroll
        for (int i = 0; i < 4; ++i) {
          int row = m0 + mf * 16 + lg * 4 + i;
          int b = row >> 11, s = row & 2047;
          o[((size_t)(b * 16 + h) * 2048 + s) * 64 + hd] = (_Float16)(acc[mf][nf][i] + bb);
        }
    }
  }
}

// --------------------------------------------------------- output GEMM (f32)
// (r22-verbatim)
__global__ __launch_bounds__(256) void out_gemm(
    const _Float16* __restrict__ attn, const _Float16* __restrict__ wo,
    const float* __restrict__ bo, float* __restrict__ out) {
  __shared__ __align__(16) _Float16 smem[12288];
  _Float16* As = smem;
  _Float16* Bs = smem + 4096;
  int tid = threadIdx.x;
  int m0 = blockIdx.x * 64, n0 = blockIdx.y * 128;
  f32x4 acc[4][2] = {};
  gemm_core64(attn, wo, As, Bs, acc, m0, n0, tid);

  int lane = tid & 63, wid = tid >> 6;
  int lr = lane & 15, lg = lane >> 4;
  int wn = wid * 32;
#pragma unroll
  for (int nf = 0; nf < 2; ++nf) {
    int col = n0 + wn + nf * 16 + lr;
    float bb = bo[col];
#pragma unroll
    for (int mf = 0; mf < 4; ++mf)
#pragma unroll
      for (int i = 0; i < 4; ++i) {
        int row = m0 + mf * 16 + lg * 4 + i;
        out[(size_t)row * 1024 + col] = acc[mf][nf][i] + bb;
      }
  }
}

// --------------------------------------------------------- flash attention v17
// (byte-identical to r21/r22 — PASSED at 46us)
#define LDP 72  // padded LDS stride (halves)

template <bool MASK>
__device__ __forceinline__ void attn_tile32(const _Float16* Ks, const _Float16* Vs,
                                            const f16x8 qb[2][2], int kv0, int qwb,
                                            int lr, int lg,
                                            float m[2], float l[2], f32x4 ot[2][4]) {
  const float L2E = 1.44269504f;
  const float NINF = -__builtin_inff();
  f16x8 kf0[4], kf1[4];
#pragma unroll
  for (int nf = 0; nf < 4; ++nf) {
    kf0[nf] = *(const f16x8*)(Ks + (nf * 16 + lr) * LDP + lg * 8);
    kf1[nf] = *(const f16x8*)(Ks + (nf * 16 + lr) * LDP + 32 + lg * 8);
  }
  f32x4 sc[2][4];
#pragma unroll
  for (int h = 0; h < 2; ++h)
#pragma unroll
    for (int nf = 0; nf < 4; ++nf) {
      f32x4 z = {0.f, 0.f, 0.f, 0.f};
      z = MFMA32(kf0[nf], qb[h][0], z);
      z = MFMA32(kf1[nf], qb[h][1], z);
      sc[h][nf] = z;
    }
  if (MASK) {
#pragma unroll
    for (int h = 0; h < 2; ++h) {
      int qg = qwb + h * 16 + lr;
#pragma unroll
      for (int nf = 0; nf < 4; ++nf)
#pragma unroll
        for (int i = 0; i < 4; ++i) {
          int kg = kv0 + nf * 16 + lg * 4 + i;
          sc[h][nf][i] = (kg <= qg) ? sc[h][nf][i] : NINF;
        }
    }
  }
  f16x4 pf[2][4];
#pragma unroll
  for (int h = 0; h < 2; ++h) {
    f32x4 mx4 = sc[h][0];
#pragma unroll
    for (int nf = 1; nf < 4; ++nf)
#pragma unroll
      for (int i = 0; i < 4; ++i) mx4[i] = fmaxf(mx4[i], sc[h][nf][i]);
    float tm = fmaxf(fmaxf(mx4[0], mx4[1]), fmaxf(mx4[2], mx4[3]));
    tm = fmaxf(tm, __shfl_xor(tm, 16));
    tm = fmaxf(tm, __shfl_xor(tm, 32));
    float mn = fmaxf(m[h], tm);
    float alpha = __builtin_amdgcn_exp2f((m[h] - mn) * L2E);
    m[h] = mn;
    float mnL = mn * L2E;
    float ps = 0.f;
#pragma unroll
    for (int nf = 0; nf < 4; ++nf)
#pragma unroll
      for (int i = 0; i < 4; ++i) {
        float p = __builtin_amdgcn_exp2f(sc[h][nf][i] * L2E - mnL);
        ps += p;
        pf[h][nf][i] = (_Float16)p;
      }
    ps += __shfl_xor(ps, 16);
    ps += __shfl_xor(ps, 32);
    l[h] = l[h] * alpha + ps;
#pragma unroll
    for (int dt = 0; dt < 4; ++dt)
#pragma unroll
      for (int i = 0; i < 4; ++i) ot[h][dt][i] *= alpha;
  }
#pragma unroll
  for (int nf = 0; nf < 4; ++nf)
#pragma unroll
    for (int dt = 0; dt < 4; ++dt) {
      f16x4 vf = *(const f16x4*)(Vs + (dt * 16 + lr) * LDP + nf * 16 + lg * 4);
      ot[0][dt] = MFMA16(vf, pf[0][nf], ot[0][dt]);
      ot[1][dt] = MFMA16(vf, pf[1][nf], ot[1][dt]);
    }
}

__global__ __launch_bounds__(512, 2) void attn_kernel(
    const _Float16* __restrict__ Q, const _Float16* __restrict__ K,
    const _Float16* __restrict__ VT, _Float16* __restrict__ O) {
  __shared__ __align__(16) _Float16 smem[18432];
  _Float16* KsA = smem;
  _Float16* KsB = smem + 4608;
  _Float16* VsA = smem + 9216;
  _Float16* VsB = smem + 13824;
  const float L2E = 1.44269504f;

  int tid = threadIdx.x, lane = tid & 63, wid = tid >> 6;
  int grp = wid >> 2;
  int wq4 = wid & 3;
  int hh = blockIdx.x;
  int qt = blockIdx.z ? (15 - (int)blockIdx.y) : (int)blockIdx.y;
  int b = blockIdx.z;
  size_t hoff = (size_t)(b * 16 + hh) * 2048 * 64;
  const _Float16* Qh = Q + hoff;
  const _Float16* Kh = K + hoff;
  const _Float16* VTh = VT + hoff;
  int qwb = qt * 128 + wq4 * 32;
  int lr = lane & 15, lg = lane >> 4;

  f16x8 qb[2][2];
#pragma unroll
  for (int h = 0; h < 2; ++h) {
    const _Float16* qp = Qh + (size_t)(qwb + h * 16 + lr) * 64;
    qb[h][0] = *(const f16x8*)(qp + lg * 8);
    qb[h][1] = *(const f16x8*)(qp + 32 + lg * 8);
#pragma unroll
    for (int j = 0; j < 8; ++j) {
      qb[h][0][j] *= (_Float16)0.125f;
      qb[h][1][j] *= (_Float16)0.125f;
    }
  }

  float m[2] = {-__builtin_inff(), -__builtin_inff()};
  float l[2] = {0.f, 0.f};
  f32x4 ot[2][4] = {};

  int rr = tid >> 3, cc = (tid & 7) * 8;
  int4 rka = *(const int4*)(Kh + (size_t)rr * 64 + cc);
  int4 rkb = *(const int4*)(Kh + (size_t)(64 + rr) * 64 + cc);
  int4 rva = *(const int4*)(VTh + (size_t)rr * 2048 + cc);
  int4 rvb = *(const int4*)(VTh + (size_t)rr * 2048 + 64 + cc);
  *(int4*)(KsA + rr * LDP + cc) = rka;
  *(int4*)(KsB + rr * LDP + cc) = rkb;
  *(int4*)(VsA + rr * LDP + cc) = rva;
  *(int4*)(VsB + rr * LDP + cc) = rvb;
  __syncthreads();

  int aw = qwb >> 6;
  for (int p = 0; p <= qt; ++p) {
    if (p < qt) {
      int ka = (p + 1) * 128, kb = ka + 64;
      rka = *(const int4*)(Kh + (size_t)(ka + rr) * 64 + cc);
      rkb = *(const int4*)(Kh + (size_t)(kb + rr) * 64 + cc);
      rva = *(const int4*)(VTh + (size_t)rr * 2048 + ka + cc);
      rvb = *(const int4*)(VTh + (size_t)rr * 2048 + kb + cc);
    }
    int tm = 2 * p + grp;
    const _Float16* Ks = grp ? KsB : KsA;
    const _Float16* Vs = grp ? VsB : VsA;
    if (tm < aw)
      attn_tile32<false>(Ks, Vs, qb, tm * 64, qwb, lr, lg, m, l, ot);
    else if (tm == aw)
      attn_tile32<true>(Ks, Vs, qb, tm * 64, qwb, lr, lg, m, l, ot);
    __syncthreads();
    if (p < qt) {
      *(int4*)(KsA + rr * LDP + cc) = rka;
      *(int4*)(KsB + rr * LDP + cc) = rkb;
      *(int4*)(VsA + rr * LDP + cc) = rva;
      *(int4*)(VsB + rr * LDP + cc) = rvb;
      __syncthreads();
    }
  }

  float* Cmb = (float*)smem;
  if (grp == 1) {
    int base = wq4 * 64 + lane;
#pragma unroll
    for (int h = 0; h < 2; ++h) {
      Cmb[(h * 18 + 0) * 256 + base] = m[h];
      Cmb[(h * 18 + 1) * 256 + base] = l[h];
#pragma unroll
      for (int dt = 0; dt < 4; ++dt)
#pragma unroll
        for (int i = 0; i < 4; ++i)
          Cmb[(h * 18 + 2 + dt * 4 + i) * 256 + base] = ot[h][dt][i];
    }
  }
  __syncthreads();
  if (grp == 0) {
    int base = wq4 * 64 + lane;
#pragma unroll
    for (int h = 0; h < 2; ++h) {
      float mB = Cmb[(h * 18 + 0) * 256 + base];
      float lB = Cmb[(h * 18 + 1) * 256 + base];
      float ms = fmaxf(m[h], mB);
      float fA = __builtin_amdgcn_exp2f((m[h] - ms) * L2E);
      float fB = __builtin_amdgcn_exp2f((mB - ms) * L2E);
      float inv = 1.f / (fA * l[h] + fB * lB);
      fA *= inv; fB *= inv;
      _Float16* Oh = O + ((size_t)b * 2048 + qwb + h * 16 + lr) * 1024 + hh * 64;
#pragma unroll
      for (int dt = 0; dt < 4; ++dt) {
        f16x4 o;
#pragma unroll
        for (int i = 0; i < 4; ++i)
          o[i] = (_Float16)(fA * ot[h][dt][i] +
                            fB * Cmb[(h * 18 + 2 + dt * 4 + i) * 256 + base]);
        *(f16x4*)(Oh + dt * 16 + lg * 4) = o;
      }
    }
  }
}

// ------------------------------------------------------------------- launch
extern "C" void kernel_launch(void* const* d_in, const int* in_sizes, int n_in,
                              void* d_out, int out_size, void* d_ws, size_t ws_size,
                              hipStream_t stream) {
  const float* x  = (const float*)d_in[0];
  const float* Wq = (const float*)d_in[1];
  const float* bq = (const float*)d_in[2];
  const float* Wk = (const float*)d_in[3];
  const float* bk = (const float*)d_in[4];
  const float* Wv = (const float*)d_in[5];
  const float* bv = (const float*)d_in[6];
  const float* Wo = (const float*)d_in[7];
  const float* bo = (const float*)d_in[8];
  float* out = (float*)d_out;

  _Float16* ws  = (_Float16*)d_ws;
  _Float16* xb  = ws;
  _Float16* wqb = ws + 4194304;
  _Float16* wkb = ws + 5242880;
  _Float16* wvb = ws + 6291456;
  _Float16* wob = ws + 7340032;
  _Float16* qw  = ws + 8388608;       // [B,H,S,64]
  _Float16* kw  = ws + 12582912;      // [B,H,S,64]
  _Float16* vtw = ws + 16777216;      // [B,H,64,S]
  _Float16* aw  = ws + 20971520;      // [B,S,1024]

  convert_all<<<8192, 256, 0, stream>>>(x, Wq, Wk, Wv, Wo,
                                        xb, wqb, wkb, wvb, wob);

  proj_gemm<<<dim3(64, 8, 3), 128, 0, stream>>>(xb, wqb, wkb, wvb, bq, bk, bv,
                                                qw, kw, vtw);
  attn_kernel<<<dim3(16, 16, 2), 512, 0, stream>>>(qw, kw, vtw, aw);
  out_gemm<<<dim3(64, 8), 256, 0, stream>>>(aw, wob, bo, out);
}

// Round 25
// 102.546 us; speedup vs baseline: 1.1337x; 1.0879x over previous
//
#include <hip/hip_runtime.h>

typedef _Float16 f16x8 __attribute__((ext_vector_type(8)));
typedef _Float16 f16x4 __attribute__((ext_vector_type(4)));
typedef float f32x4 __attribute__((ext_vector_type(4)));

#define MFMA32(a, b, c) __builtin_amdgcn_mfma_f32_16x16x32_f16(a, b, c, 0, 0, 0)
#define MFMA16(a, b, c) __builtin_amdgcn_mfma_f32_16x16x16f16(a, b, c, 0, 0, 0)

// ---------------------------------------------------------------- converts
__global__ __launch_bounds__(256) void convert_all(
    const float* __restrict__ x,
    const float* __restrict__ w0, const float* __restrict__ w1,
    const float* __restrict__ w2, const float* __restrict__ w3,
    _Float16* __restrict__ xb,
    _Float16* __restrict__ o0, _Float16* __restrict__ o1,
    _Float16* __restrict__ o2, _Float16* __restrict__ o3) {
  int chunk = blockIdx.x * 256 + threadIdx.x;
  const float* in;
  _Float16* out;
  int i;
  if (chunk < 1048576) {
    in = x; out = xb; i = chunk * 4;
  } else {
    int t = chunk - 1048576;
    int z = t >> 18;
    i = (t & 262143) * 4;
    in = (z == 0) ? w0 : (z == 1) ? w1 : (z == 2) ? w2 : w3;
    out = (z == 0) ? o0 : (z == 1) ? o1 : (z == 2) ? o2 : o3;
  }
  float4 v = *(const float4*)(in + i);
  f16x4 h;
  h.x = (_Float16)v.x; h.y = (_Float16)v.y; h.z = (_Float16)v.z; h.w = (_Float16)v.w;
  *(f16x4*)(out + i) = h;
}

// ---------------------------------------------------------------- staging
// T2 swizzle via PRE-SWIZZLED GLOBAL SOURCE (r22-proven): lane loads global
// chunk (lane&7)^(row&7) -> LDS chunk c of row R holds global chunk c^(R&7).
// Fragment reads XOR the same key. Bank spread: 16-way conflict -> 2-way.
__device__ __forceinline__ void gld_lds16(_Float16* l, const _Float16* g) {
  __builtin_amdgcn_global_load_lds(
      (const __attribute__((address_space(1))) unsigned int*)g,
      (__attribute__((address_space(3))) unsigned int*)l, 16, 0, 0);
}

__device__ __forceinline__ void stage64(_Float16* lds, const _Float16* g,
                                        int wid, int lane) {
  int rl = (lane >> 3) & 7;
  int col = ((lane & 7) ^ rl) * 8;           // pre-swizzled source column
#pragma unroll
  for (int j = 0; j < 2; ++j) {
    int blk = wid * 2 + j;
    int row = blk * 8 + rl;
    gld_lds16(lds + blk * 512, g + (size_t)row * 1024 + col);
  }
}

__device__ __forceinline__ void stage128(_Float16* lds, const _Float16* g,
                                         int wid, int lane) {
  int rl = (lane >> 3) & 7;
  int col = ((lane & 7) ^ rl) * 8;           // pre-swizzled source column
#pragma unroll
  for (int j = 0; j < 4; ++j) {
    int blk = wid * 4 + j;
    int row = blk * 8 + rl;
    gld_lds16(lds + blk * 512, g + (size_t)row * 1024 + col);
  }
}

// single-GEMM core (64x128 tile, BK=64, single-buffer, 2 barriers/K-step —
// proven r9-r22 structure) + swizzled fragment reads matching the staging.
__device__ __forceinline__ void gemm_core64(const _Float16* __restrict__ A,
                                            const _Float16* __restrict__ W,
                                            _Float16* As, _Float16* Bs,
                                            f32x4 acc[4][2], int m0, int n0, int tid) {
  int lane = tid & 63, wid = tid >> 6;
  int lr = lane & 15, lg = lane >> 4;
  int wn = wid * 32;
  int key = lr & 7;                          // row&7 for rows mf*16+lr etc.
  for (int k0 = 0; k0 < 1024; k0 += 64) {
    __syncthreads();
    stage64(As, A + (size_t)m0 * 1024 + k0, wid, lane);
    stage128(Bs, W + (size_t)n0 * 1024 + k0, wid, lane);
    __syncthreads();
#pragma unroll
    for (int ks = 0; ks < 2; ++ks) {
      int coff = ((ks * 4 + lg) ^ key) << 3; // swizzled chunk offset (halves)
      f16x8 af[4], bfv[2];
#pragma unroll
      for (int mf = 0; mf < 4; ++mf)
        af[mf] = *(const f16x8*)(As + (mf * 16 + lr) * 64 + coff);
#pragma unroll
      for (int nf = 0; nf < 2; ++nf)
        bfv[nf] = *(const f16x8*)(Bs + (wn + nf * 16 + lr) * 64 + coff);
#pragma unroll
      for (int mf = 0; mf < 4; ++mf)
#pragma unroll
        for (int nf = 0; nf < 2; ++nf)
          acc[mf][nf] = MFMA32(af[mf], bfv[nf], acc[mf][nf]);
    }
  }
}

// --------------------------------------------------- QKV projection GEMM
#define TRP 72

__global__ __launch_bounds__(256) void proj_gemm(
    const _Float16* __restrict__ xb,
    const _Float16* __restrict__ wq, const _Float16* __restrict__ wk,
    const _Float16* __restrict__ wv,
    const float* __restrict__ bq, const float* __restrict__ bk,
    const float* __restrict__ bv,
    _Float16* __restrict__ qo, _Float16* __restrict__ ko, _Float16* __restrict__ vo) {
  __shared__ __align__(16) _Float16 smem[12288];   // As 4096 + Bs 8192 halves
  _Float16* As = smem;
  _Float16* Bs = smem + 4096;
  int z = blockIdx.z;
  const _Float16* W = (z == 0) ? wq : ((z == 1) ? wk : wv);
  const float* bias = (z == 0) ? bq : ((z == 1) ? bk : bv);
  int tid = threadIdx.x;
  int m0 = blockIdx.x * 64, n0 = blockIdx.y * 128;
  f32x4 acc[4][2] = {};
  gemm_core64(xb, W, As, Bs, acc, m0, n0, tid);

  int lane = tid & 63, wid = tid >> 6;
  int lr = lane & 15, lg = lane >> 4;
  int wn = wid * 32;

  if (z == 2) {
    _Float16* Tr = smem;                 // reuse As/Bs: 128*72 = 9216 <= 12288
    int b = m0 >> 11, s0 = m0 & 2047;
    __syncthreads();
#pragma unroll
    for (int nf = 0; nf < 2; ++nf) {
      int c = wn + nf * 16 + lr;
      float bb = bias[n0 + c];
#pragma unroll
      for (int mf = 0; mf < 4; ++mf)
#pragma unroll
        for (int i = 0; i < 4; ++i)
          Tr[c * TRP + mf * 16 + lg * 4 + i] = (_Float16)(acc[mf][nf][i] + bb);
    }
    __syncthreads();
#pragma unroll
    for (int j = 0; j < 4; ++j) {
      int cid = tid + 256 * j;
      int c = cid >> 3, seg = cid & 7;
      int cg = n0 + c, h = cg >> 6, hd = cg & 63;
      f16x8 v = *(const f16x8*)(Tr + c * TRP + seg * 8);
      *(f16x8*)(vo + ((size_t)(b * 16 + h) * 64 + hd) * 2048 + s0 + seg * 8) = v;
    }
  } else {
    _Float16* o = (z == 0) ? qo : ko;
#pragma unroll
    for (int nf = 0; nf < 2; ++nf) {
      int col = n0 + wn + nf * 16 + lr;
      float bb = bias[col];
      int h = col >> 6, hd = col & 63;
#pragma unroll
      for (int mf = 0; mf < 4; ++mf)
#pragma unroll
        for (int i = 0; i < 4; ++i) {
          int row = m0 + mf * 16 + lg * 4 + i;
          int b = row >> 11, s = row & 2047;
          o[((size_t)(b * 16 + h) * 2048 + s) * 64 + hd] = (_Float16)(acc[mf][nf][i] + bb);
        }
    }
  }
}

// --------------------------------------------------------- output GEMM (f32)
__global__ __launch_bounds__(256) void out_gemm(
    const _Float16* __restrict__ attn, const _Float16* __restrict__ wo,
    const float* __restrict__ bo, float* __restrict__ out) {
  __shared__ __align__(16) _Float16 smem[12288];
  _Float16* As = smem;
  _Float16* Bs = smem + 4096;
  int tid = threadIdx.x;
  int m0 = blockIdx.x * 64, n0 = blockIdx.y * 128;
  f32x4 acc[4][2] = {};
  gemm_core64(attn, wo, As, Bs, acc, m0, n0, tid);

  int lane = tid & 63, wid = tid >> 6;
  int lr = lane & 15, lg = lane >> 4;
  int wn = wid * 32;
#pragma unroll
  for (int nf = 0; nf < 2; ++nf) {
    int col = n0 + wn + nf * 16 + lr;
    float bb = bo[col];
#pragma unroll
    for (int mf = 0; mf < 4; ++mf)
#pragma unroll
      for (int i = 0; i < 4; ++i) {
        int row = m0 + mf * 16 + lg * 4 + i;
        out[(size_t)row * 1024 + col] = acc[mf][nf][i] + bb;
      }
  }
}

// --------------------------------------------------------- flash attention v17
// (r21/r22-proven: kv-parity split, 512 thr, launch_bounds(512,2),
// in-LDS combine, complementary qt, head-x grid.)
#define LDP 72  // padded LDS stride (halves)

template <bool MASK>
__device__ __forceinline__ void attn_tile32(const _Float16* Ks, const _Float16* Vs,
                                            const f16x8 qb[2][2], int kv0, int qwb,
                                            int lr, int lg,
                                            float m[2], float l[2], f32x4 ot[2][4]) {
  const float L2E = 1.44269504f;
  const float NINF = -__builtin_inff();
  f16x8 kf0[4], kf1[4];
#pragma unroll
  for (int nf = 0; nf < 4; ++nf) {
    kf0[nf] = *(const f16x8*)(Ks + (nf * 16 + lr) * LDP + lg * 8);
    kf1[nf] = *(const f16x8*)(Ks + (nf * 16 + lr) * LDP + 32 + lg * 8);
  }
  f32x4 sc[2][4];
#pragma unroll
  for (int h = 0; h < 2; ++h)
#pragma unroll
    for (int nf = 0; nf < 4; ++nf) {
      f32x4 z = {0.f, 0.f, 0.f, 0.f};
      z = MFMA32(kf0[nf], qb[h][0], z);
      z = MFMA32(kf1[nf], qb[h][1], z);
      sc[h][nf] = z;
    }
  if (MASK) {
#pragma unroll
    for (int h = 0; h < 2; ++h) {
      int qg = qwb + h * 16 + lr;
#pragma unroll
      for (int nf = 0; nf < 4; ++nf)
#pragma unroll
        for (int i = 0; i < 4; ++i) {
          int kg = kv0 + nf * 16 + lg * 4 + i;
          sc[h][nf][i] = (kg <= qg) ? sc[h][nf][i] : NINF;
        }
    }
  }
  f16x4 pf[2][4];
#pragma unroll
  for (int h = 0; h < 2; ++h) {
    f32x4 mx4 = sc[h][0];
#pragma unroll
    for (int nf = 1; nf < 4; ++nf)
#pragma unroll
      for (int i = 0; i < 4; ++i) mx4[i] = fmaxf(mx4[i], sc[h][nf][i]);
    float tm = fmaxf(fmaxf(mx4[0], mx4[1]), fmaxf(mx4[2], mx4[3]));
    tm = fmaxf(tm, __shfl_xor(tm, 16));
    tm = fmaxf(tm, __shfl_xor(tm, 32));
    float mn = fmaxf(m[h], tm);
    float alpha = __builtin_amdgcn_exp2f((m[h] - mn) * L2E);
    m[h] = mn;
    float mnL = mn * L2E;
    float ps = 0.f;
#pragma unroll
    for (int nf = 0; nf < 4; ++nf)
#pragma unroll
      for (int i = 0; i < 4; ++i) {
        float p = __builtin_amdgcn_exp2f(sc[h][nf][i] * L2E - mnL);
        ps += p;
        pf[h][nf][i] = (_Float16)p;
      }
    ps += __shfl_xor(ps, 16);
    ps += __shfl_xor(ps, 32);
    l[h] = l[h] * alpha + ps;
#pragma unroll
    for (int dt = 0; dt < 4; ++dt)
#pragma unroll
      for (int i = 0; i < 4; ++i) ot[h][dt][i] *= alpha;
  }
#pragma unroll
  for (int nf = 0; nf < 4; ++nf)
#pragma unroll
    for (int dt = 0; dt < 4; ++dt) {
      f16x4 vf = *(const f16x4*)(Vs + (dt * 16 + lr) * LDP + nf * 16 + lg * 4);
      ot[0][dt] = MFMA16(vf, pf[0][nf], ot[0][dt]);
      ot[1][dt] = MFMA16(vf, pf[1][nf], ot[1][dt]);
    }
}

__global__ __launch_bounds__(512, 2) void attn_kernel(
    const _Float16* __restrict__ Q, const _Float16* __restrict__ K,
    const _Float16* __restrict__ VT, _Float16* __restrict__ O) {
  __shared__ __align__(16) _Float16 smem[18432];
  _Float16* KsA = smem;
  _Float16* KsB = smem + 4608;
  _Float16* VsA = smem + 9216;
  _Float16* VsB = smem + 13824;
  const float L2E = 1.44269504f;

  int tid = threadIdx.x, lane = tid & 63, wid = tid >> 6;
  int grp = wid >> 2;                  // 0: even tiles, 1: odd tiles
  int wq4 = wid & 3;                   // q sub-block within group
  int hh = blockIdx.x;                 // head on x -> XCD = hh%8 (K/V L2-local)
  int qt = blockIdx.z ? (15 - (int)blockIdx.y) : (int)blockIdx.y;
  int b = blockIdx.z;
  size_t hoff = (size_t)(b * 16 + hh) * 2048 * 64;
  const _Float16* Qh = Q + hoff;
  const _Float16* Kh = K + hoff;
  const _Float16* VTh = VT + hoff;
  int qwb = qt * 128 + wq4 * 32;
  int lr = lane & 15, lg = lane >> 4;

  f16x8 qb[2][2];
#pragma unroll
  for (int h = 0; h < 2; ++h) {
    const _Float16* qp = Qh + (size_t)(qwb + h * 16 + lr) * 64;
    qb[h][0] = *(const f16x8*)(qp + lg * 8);
    qb[h][1] = *(const f16x8*)(qp + 32 + lg * 8);
#pragma unroll
    for (int j = 0; j < 8; ++j) {      // fold 1/sqrt(64) into Q (exact: 2^-3)
      qb[h][0][j] *= (_Float16)0.125f;
      qb[h][1][j] *= (_Float16)0.125f;
    }
  }

  float m[2] = {-__builtin_inff(), -__builtin_inff()};
  float l[2] = {0.f, 0.f};
  f32x4 ot[2][4] = {};

  int rr = tid >> 3, cc = (tid & 7) * 8;    // rr in 0..63
  int4 rka = *(const int4*)(Kh + (size_t)rr * 64 + cc);
  int4 rkb = *(const int4*)(Kh + (size_t)(64 + rr) * 64 + cc);
  int4 rva = *(const int4*)(VTh + (size_t)rr * 2048 + cc);
  int4 rvb = *(const int4*)(VTh + (size_t)rr * 2048 + 64 + cc);
  *(int4*)(KsA + rr * LDP + cc) = rka;
  *(int4*)(KsB + rr * LDP + cc) = rkb;
  *(int4*)(VsA + rr * LDP + cc) = rva;
  *(int4*)(VsB + rr * LDP + cc) = rvb;
  __syncthreads();

  int aw = qwb >> 6;                   // this wave's masked tile (global index)
  for (int p = 0; p <= qt; ++p) {
    if (p < qt) {                      // issue pair p+1 loads before compute
      int ka = (p + 1) * 128, kb = ka + 64;
      rka = *(const int4*)(Kh + (size_t)(ka + rr) * 64 + cc);
      rkb = *(const int4*)(Kh + (size_t)(kb + rr) * 64 + cc);
      rva = *(const int4*)(VTh + (size_t)rr * 2048 + ka + cc);
      rvb = *(const int4*)(VTh + (size_t)rr * 2048 + kb + cc);
    }
    int tm = 2 * p + grp;              // this group's tile this pair
    const _Float16* Ks = grp ? KsB : KsA;
    const _Float16* Vs = grp ? VsB : VsA;
    if (tm < aw)
      attn_tile32<false>(Ks, Vs, qb, tm * 64, qwb, lr, lg, m, l, ot);
    else if (tm == aw)
      attn_tile32<true>(Ks, Vs, qb, tm * 64, qwb, lr, lg, m, l, ot);
    __syncthreads();                   // all reads of pair p complete
    if (p < qt) {
      *(int4*)(KsA + rr * LDP + cc) = rka;
      *(int4*)(KsB + rr * LDP + cc) = rkb;
      *(int4*)(VsA + rr * LDP + cc) = rva;
      *(int4*)(VsB + rr * LDP + cc) = rvb;
      __syncthreads();                 // pair p+1 visible
    }
  }

  // ---- intra-block combine: group B -> LDS, group A merges and writes O ----
  float* Cmb = (float*)smem;           // 36*256*4 = 36864 B (exact reuse)
  if (grp == 1) {
    int base = wq4 * 64 + lane;
#pragma unroll
    for (int h = 0; h < 2; ++h) {
      Cmb[(h * 18 + 0) * 256 + base] = m[h];
      Cmb[(h * 18 + 1) * 256 + base] = l[h];
#pragma unroll
      for (int dt = 0; dt < 4; ++dt)
#pragma unroll
        for (int i = 0; i < 4; ++i)
          Cmb[(h * 18 + 2 + dt * 4 + i) * 256 + base] = ot[h][dt][i];
    }
  }
  __syncthreads();
  if (grp == 0) {
    int base = wq4 * 64 + lane;
#pragma unroll
    for (int h = 0; h < 2; ++h) {
      float mB = Cmb[(h * 18 + 0) * 256 + base];
      float lB = Cmb[(h * 18 + 1) * 256 + base];
      float ms = fmaxf(m[h], mB);
      float fA = __builtin_amdgcn_exp2f((m[h] - ms) * L2E);
      float fB = __builtin_amdgcn_exp2f((mB - ms) * L2E);
      float inv = 1.f / (fA * l[h] + fB * lB);
      fA *= inv; fB *= inv;
      _Float16* Oh = O + ((size_t)b * 2048 + qwb + h * 16 + lr) * 1024 + hh * 64;
#pragma unroll
      for (int dt = 0; dt < 4; ++dt) {
        f16x4 o;
#pragma unroll
        for (int i = 0; i < 4; ++i)
          o[i] = (_Float16)(fA * ot[h][dt][i] +
                            fB * Cmb[(h * 18 + 2 + dt * 4 + i) * 256 + base]);
        *(f16x4*)(Oh + dt * 16 + lg * 4) = o;
      }
    }
  }
}

// ------------------------------------------------------------------- launch
extern "C" void kernel_launch(void* const* d_in, const int* in_sizes, int n_in,
                              void* d_out, int out_size, void* d_ws, size_t ws_size,
                              hipStream_t stream) {
  const float* x  = (const float*)d_in[0];
  const float* Wq = (const float*)d_in[1];
  const float* bq = (const float*)d_in[2];
  const float* Wk = (const float*)d_in[3];
  const float* bk = (const float*)d_in[4];
  const float* Wv = (const float*)d_in[5];
  const float* bv = (const float*)d_in[6];
  const float* Wo = (const float*)d_in[7];
  const float* bo = (const float*)d_in[8];
  float* out = (float*)d_out;

  _Float16* ws  = (_Float16*)d_ws;
  _Float16* xb  = ws;
  _Float16* wqb = ws + 4194304;
  _Float16* wkb = ws + 5242880;
  _Float16* wvb = ws + 6291456;
  _Float16* wob = ws + 7340032;
  _Float16* qw  = ws + 8388608;       // [B,H,S,64]
  _Float16* kw  = ws + 12582912;      // [B,H,S,64]
  _Float16* vtw = ws + 16777216;      // [B,H,64,S]
  _Float16* aw  = ws + 20971520;      // [B,S,1024]

  convert_all<<<8192, 256, 0, stream>>>(x, Wq, Wk, Wv, Wo,
                                        xb, wqb, wkb, wvb, wob);

  proj_gemm<<<dim3(64, 8, 3), 256, 0, stream>>>(xb, wqb, wkb, wvb, bq, bk, bv,
                                                qw, kw, vtw);
  attn_kernel<<<dim3(16, 16, 2), 512, 0, stream>>>(qw, kw, vtw, aw);
  out_gemm<<<dim3(64, 8), 256, 0, stream>>>(aw, wob, bo, out);
}